// Round 5
// baseline (514.515 us; speedup 1.0000x reference)
//
#include <hip/hip_runtime.h>

// B=16384, F=40, D=32, fp32 — fused single kernel, intermediates in LDS.
// Block = 256 thr = 4 waves, NB=4 batch elements; wave w owns fields
// [10w,10w+10). 20 KB LDS.
//   phase 0: stage h[b][f][d]            (coalesced bulk copy)
//   stage A: h_out = Wout[f] @ h         FULL-UNROLLED fi, accumulate in
//            accA regs (NO ds_writes between reads -> compiler pipelines
//            the 80 W-loads + 160 LDS reads); one wave-private write pass.
//   stage B: aggr = g @ h_out            regs; barrier; write in-place
//   stage C: out  = Win[f] @ aggr + bias FULL-UNROLLED fi; global stores
//            (wave-local rows: lgkmcnt(0) suffices, no barrier)
// R4 lesson: '#pragma unroll 1' + in-place RAW serialized each fi on a
// ~200-900cyc W-load -> duty 4%, 352us. R2 proved full unroll + reg
// accumulation pipelines W loads (230us). This = R2 scheduling + R4
// occupancy/barrier structure. WRITE_SIZE==81920KB is the spill tripwire.

#define B_TOT 16384
#define FF    40
#define DD    32
#define NB    4
#define WF    10

__global__ __launch_bounds__(256, 4)   // allow up to 128 VGPR for pipelining
void graph_layer_fused(const float* __restrict__ g,
                       const float* __restrict__ h,
                       const float* __restrict__ Win,
                       const float* __restrict__ Wout,
                       const float* __restrict__ bias,
                       float* __restrict__ out)
{
    __shared__ __attribute__((aligned(16))) float s_buf[NB * FF * DD]; // 20 KB

    const int t     = threadIdx.x;
    const int w     = t >> 6;
    const int l     = t & 63;
    const int b0    = blockIdx.x * NB;
    const int fbase = w * WF;

    // ---- phase 0: bulk-stage h for 4 b's, linear [b][f][d] ----------------
    {
        const float4* src = (const float4*)(h + (size_t)b0 * (FF * DD));
        float4* dst = (float4*)s_buf;
        #pragma unroll
        for (int k = 0; k < 5; ++k)
            dst[t + k * 256] = src[t + k * 256];
    }
    __syncthreads();

    // ---- stage A: h_out = Wout[f] @ h[b,f,:], acc in regs, then write ----
    const int d    = l & 31;
    const int half = l >> 5;
    float accA[WF][2];
    #pragma unroll
    for (int fi = 0; fi < WF; ++fi) {              // FULL unroll: 80 W loads
        const int f = fbase + fi;                  // + 160 LDS reads, all
        const float4* wrow = (const float4*)(Wout + ((size_t)f * DD + d) * DD);
        float4 wr[8];                              // independent -> pipeline
        #pragma unroll
        for (int j = 0; j < 8; ++j) wr[j] = wrow[j];
        #pragma unroll
        for (int bp = 0; bp < 2; ++bp) {
            const int bl = 2 * bp + half;
            const float4* row = (const float4*)(s_buf + (bl * FF + f) * DD);
            float p0 = 0.f, p1 = 0.f, p2 = 0.f, p3 = 0.f;
            #pragma unroll
            for (int j = 0; j < 8; ++j) {          // 2-addr broadcast reads
                float4 hv = row[j];
                p0 += wr[j].x * hv.x; p1 += wr[j].y * hv.y;
                p2 += wr[j].z * hv.z; p3 += wr[j].w * hv.w;
            }
            accA[fi][bp] = (p0 + p1) + (p2 + p3);
        }
    }
    // wave-private rows; all reads above precede these writes in program
    // order (same-wave DS ordering) -> no barrier needed here
    #pragma unroll
    for (int fi = 0; fi < WF; ++fi)
        #pragma unroll
        for (int bp = 0; bp < 2; ++bp)
            s_buf[((2 * bp + half) * FF + fbase + fi) * DD + d] = accA[fi][bp];
    __syncthreads();                       // h_out complete for all waves

    // ---- stage B: aggr = sum_G g[b,f,G] * h_out[b,G,:] --------------------
    // lane: bl = l>>4 (0..3), dq = (l>>1)&7, fh = l&1 (field half)
    const int bl = l >> 4;
    const int dq = (l >> 1) & 7;
    const int fh = l & 1;
    const int f0 = fbase + fh * 5;
    const float* grow = g + (size_t)(b0 + bl) * (FF * FF) + (size_t)f0 * FF;
    const float* sbB  = s_buf + bl * (FF * DD) + dq * 4;

    float4 accB[5];
    float4 gv[5];
    #pragma unroll
    for (int fi = 0; fi < 5; ++fi) {
        accB[fi] = make_float4(0.f, 0.f, 0.f, 0.f);
        gv[fi]   = *(const float4*)(grow + fi * FF);      // prefetch gc=0
    }
    #pragma unroll 1
    for (int gc = 0; gc < 10; ++gc) {
        const int gnx = (gc < 9) ? 4 * gc + 4 : 36;       // rolling prefetch
        float4 h0 = *(const float4*)(sbB + (4 * gc + 0) * DD);
        float4 h1 = *(const float4*)(sbB + (4 * gc + 1) * DD);
        #pragma unroll
        for (int fi = 0; fi < 5; ++fi) {
            float4 gf = gv[fi];
            accB[fi].x += gf.x * h0.x + gf.y * h1.x;
            accB[fi].y += gf.x * h0.y + gf.y * h1.y;
            accB[fi].z += gf.x * h0.z + gf.y * h1.z;
            accB[fi].w += gf.x * h0.w + gf.y * h1.w;
        }
        float4 h2 = *(const float4*)(sbB + (4 * gc + 2) * DD);
        float4 h3 = *(const float4*)(sbB + (4 * gc + 3) * DD);
        #pragma unroll
        for (int fi = 0; fi < 5; ++fi) {
            float4 gf = gv[fi];
            accB[fi].x += gf.z * h2.x + gf.w * h3.x;
            accB[fi].y += gf.z * h2.y + gf.w * h3.y;
            accB[fi].z += gf.z * h2.z + gf.w * h3.z;
            accB[fi].w += gf.z * h2.w + gf.w * h3.w;
            gv[fi] = *(const float4*)(grow + fi * FF + gnx); // refresh after use
        }
    }
    __syncthreads();                       // all h_out reads done everywhere

    #pragma unroll
    for (int fi = 0; fi < 5; ++fi)         // aggr in place, [b][f][d]
        *(float4*)(s_buf + ((size_t)bl * FF + f0 + fi) * DD + dq * 4) = accB[fi];
    // aggr rows (bl, f in wave range) are written & read by THIS wave only:
    // drain own DS queue instead of a block barrier
    asm volatile("s_waitcnt lgkmcnt(0)" ::: "memory");

    // ---- stage C: out = Win[f] @ aggr + bias ------------------------------
    {
        const float bv = bias[d];
        #pragma unroll
        for (int fi = 0; fi < WF; ++fi) {          // FULL unroll, stores are
            const int f = fbase + fi;              // global -> no LDS hazard
            const float4* wrow = (const float4*)(Win + ((size_t)f * DD + d) * DD);
            float4 wr[8];
            #pragma unroll
            for (int j = 0; j < 8; ++j) wr[j] = wrow[j];
            #pragma unroll
            for (int bp = 0; bp < 2; ++bp) {
                const int bl2 = 2 * bp + half;
                const float4* arow = (const float4*)(s_buf + (bl2 * FF + f) * DD);
                float p0 = 0.f, p1 = 0.f, p2 = 0.f, p3 = 0.f;
                #pragma unroll
                for (int j = 0; j < 8; ++j) {
                    float4 av = arow[j];
                    p0 += wr[j].x * av.x; p1 += wr[j].y * av.y;
                    p2 += wr[j].z * av.z; p3 += wr[j].w * av.w;
                }
                out[((size_t)(b0 + bl2) * FF + f) * DD + d] =
                    ((p0 + p1) + (p2 + p3)) + bv;   // 128 B per half-wave
            }
        }
    }
}

extern "C" void kernel_launch(void* const* d_in, const int* in_sizes, int n_in,
                              void* d_out, int out_size, void* d_ws, size_t ws_size,
                              hipStream_t stream) {
    const float* g    = (const float*)d_in[0];
    const float* h    = (const float*)d_in[1];
    const float* Win  = (const float*)d_in[2];
    const float* Wout = (const float*)d_in[3];
    const float* bias = (const float*)d_in[4];
    float* out = (float*)d_out;

    dim3 block(256);
    dim3 grid(B_TOT / NB);   // 4096 blocks
    graph_layer_fused<<<grid, block, 0, stream>>>(g, h, Win, Wout, bias, out);
}

// Round 6
// 320.660 us; speedup vs baseline: 1.6046x; 1.6046x over previous
//
#include <hip/hip_runtime.h>

// B=16384, F=40, D=32, fp32 — fused, NB=16 batch elements per 256-thr block.
// The measured lever across R0-R5 is FMAs-per-serial-chain (NB=8:230us,
// NB=4:~360us, occupancy irrelevant 41..81%). So: NB=16 (80 KB LDS, 2
// blocks/CU — LDS-capped occupancy is EXPECTED; VGPRs are free to 256) and
// MANUAL W double-buffering (R5 proved the compiler remats W loads at
// VGPR=64 instead of pipelining; explicit ping-pong defeats that).
//   phase 0: bulk-stage h[16][40][32]  (coalesced, 20 f4/thread)
//   stage A: h_out = Wout[f] @ h, in place, W ping-pong 2-field loop
//   stage B: aggr = g @ h_out, 4 sequential b-groups, rolling gv, accB[4][5]
//            regs; ONE barrier; write aggr; lgkmcnt(0)
//   stage C: out = Win[f] @ aggr + bias, W ping-pong, wave-private reads
// Tripwire: WRITE_SIZE must be exactly 81920 KB (no spills, R3 lesson).

#define B_TOT 16384
#define FF    40
#define DD    32
#define NB    16
#define WF    10

__global__ __launch_bounds__(256, 2)   // LDS caps at 2 blocks/CU; VGPR<=256
void graph_layer_fused(const float* __restrict__ g,
                       const float* __restrict__ h,
                       const float* __restrict__ Win,
                       const float* __restrict__ Wout,
                       const float* __restrict__ bias,
                       float* __restrict__ out)
{
    __shared__ __attribute__((aligned(16))) float s_buf[NB * FF * DD]; // 80 KB

    const int t     = threadIdx.x;
    const int w     = t >> 6;
    const int l     = t & 63;
    const int b0    = blockIdx.x * NB;
    const int fbase = w * WF;

    // ---- phase 0: bulk-stage h for 16 b's, linear [b][f][d] ---------------
    {
        const float4* src = (const float4*)(h + (size_t)b0 * (FF * DD));
        float4* dst = (float4*)s_buf;
        #pragma unroll
        for (int k = 0; k < 20; ++k)
            dst[t + k * 256] = src[t + k * 256];
    }
    __syncthreads();

    const int d    = l & 31;
    const int half = l >> 5;

    // ---- stage A: h_out = Wout[f] @ h[b,f,:], in place, W ping-pong -------
    {
        const float4* wp = (const float4*)Wout + (size_t)(fbase * DD + d) * (DD / 4);
        float4 wA[8], wB[8];
        #pragma unroll
        for (int j = 0; j < 8; ++j) wA[j] = wp[j];            // f = fbase
        #pragma unroll 1
        for (int fp = 0; fp < WF / 2; ++fp) {
            const int f = fbase + 2 * fp;
            // issue next-field loads, then compute current (latency covered)
            const float4* wn = wp + (size_t)(2 * fp + 1) * (DD * DD / 4);
            #pragma unroll
            for (int j = 0; j < 8; ++j) wB[j] = wn[j];
            #pragma unroll
            for (int bp = 0; bp < NB / 2; ++bp) {             // even field: wA
                const int bl = (bp << 1) + half;
                float* row = s_buf + (bl * FF + f) * DD;
                float p0 = 0.f, p1 = 0.f, p2 = 0.f, p3 = 0.f;
                #pragma unroll
                for (int j = 0; j < 8; ++j) {                 // 2-addr bcast
                    float4 hv = ((const float4*)row)[j];
                    p0 += wA[j].x * hv.x; p1 += wA[j].y * hv.y;
                    p2 += wA[j].z * hv.z; p3 += wA[j].w * hv.w;
                }
                row[d] = (p0 + p1) + (p2 + p3);   // wave-private row, in order
            }
            if (fp < WF / 2 - 1) {
                const float4* wn2 = wp + (size_t)(2 * fp + 2) * (DD * DD / 4);
                #pragma unroll
                for (int j = 0; j < 8; ++j) wA[j] = wn2[j];
            }
            #pragma unroll
            for (int bp = 0; bp < NB / 2; ++bp) {             // odd field: wB
                const int bl = (bp << 1) + half;
                float* row = s_buf + (bl * FF + f + 1) * DD;
                float p0 = 0.f, p1 = 0.f, p2 = 0.f, p3 = 0.f;
                #pragma unroll
                for (int j = 0; j < 8; ++j) {
                    float4 hv = ((const float4*)row)[j];
                    p0 += wB[j].x * hv.x; p1 += wB[j].y * hv.y;
                    p2 += wB[j].z * hv.z; p3 += wB[j].w * hv.w;
                }
                row[d] = (p0 + p1) + (p2 + p3);
            }
        }
    }
    __syncthreads();                       // h_out complete for all waves

    // ---- stage B: aggr = sum_G g[b,f,G] * h_out[b,G,:] --------------------
    // lane: blq = l>>4 (0..3), dq = (l>>1)&7, fh = l&1; 4 b-groups/thread
    const int blq = l >> 4;
    const int dq  = (l >> 1) & 7;
    const int fh  = l & 1;
    const int f0  = fbase + fh * 5;

    float4 accB[4][5];                     // static indices only (rule #20)
    #pragma unroll
    for (int bg = 0; bg < 4; ++bg) {
        const int bl = bg * 4 + blq;
        const float* grow = g + (size_t)(b0 + bl) * (FF * FF) + (size_t)f0 * FF;
        const float* sbB  = s_buf + bl * (FF * DD) + dq * 4;

        float4 gv[5];
        #pragma unroll
        for (int fi = 0; fi < 5; ++fi) {
            accB[bg][fi] = make_float4(0.f, 0.f, 0.f, 0.f);
            gv[fi] = *(const float4*)(grow + fi * FF);        // prefetch gc=0
        }
        #pragma unroll 1
        for (int gc = 0; gc < 10; ++gc) {
            const int gnx = (gc < 9) ? 4 * gc + 4 : 36;       // rolling pref
            float4 h0 = *(const float4*)(sbB + (4 * gc + 0) * DD);
            float4 h1 = *(const float4*)(sbB + (4 * gc + 1) * DD);
            #pragma unroll
            for (int fi = 0; fi < 5; ++fi) {
                float4 gf = gv[fi];
                accB[bg][fi].x += gf.x * h0.x + gf.y * h1.x;
                accB[bg][fi].y += gf.x * h0.y + gf.y * h1.y;
                accB[bg][fi].z += gf.x * h0.z + gf.y * h1.z;
                accB[bg][fi].w += gf.x * h0.w + gf.y * h1.w;
            }
            float4 h2 = *(const float4*)(sbB + (4 * gc + 2) * DD);
            float4 h3 = *(const float4*)(sbB + (4 * gc + 3) * DD);
            #pragma unroll
            for (int fi = 0; fi < 5; ++fi) {
                float4 gf = gv[fi];
                accB[bg][fi].x += gf.z * h2.x + gf.w * h3.x;
                accB[bg][fi].y += gf.z * h2.y + gf.w * h3.y;
                accB[bg][fi].z += gf.z * h2.z + gf.w * h3.z;
                accB[bg][fi].w += gf.z * h2.w + gf.w * h3.w;
                gv[fi] = *(const float4*)(grow + fi * FF + gnx);
            }
        }
    }
    __syncthreads();                       // ALL waves' h_out reads done

    #pragma unroll
    for (int bg = 0; bg < 4; ++bg) {
        const int bl = bg * 4 + blq;
        #pragma unroll
        for (int fi = 0; fi < 5; ++fi)     // aggr in place, [b][f][d]
            *(float4*)(s_buf + ((size_t)bl * FF + f0 + fi) * DD + dq * 4)
                = accB[bg][fi];
    }
    // aggr rows (all bl, f in wave range) written & read by THIS wave only
    asm volatile("s_waitcnt lgkmcnt(0)" ::: "memory");

    // ---- stage C: out = Win[f] @ aggr + bias, W ping-pong -----------------
    {
        const float bv = bias[d];
        const float4* wp = (const float4*)Win + (size_t)(fbase * DD + d) * (DD / 4);
        float4 wA[8], wB[8];
        #pragma unroll
        for (int j = 0; j < 8; ++j) wA[j] = wp[j];
        #pragma unroll 1
        for (int fp = 0; fp < WF / 2; ++fp) {
            const int f = fbase + 2 * fp;
            const float4* wn = wp + (size_t)(2 * fp + 1) * (DD * DD / 4);
            #pragma unroll
            for (int j = 0; j < 8; ++j) wB[j] = wn[j];
            #pragma unroll
            for (int bp = 0; bp < NB / 2; ++bp) {             // even field
                const int bl = (bp << 1) + half;
                const float4* arow = (const float4*)(s_buf + (bl * FF + f) * DD);
                float p0 = 0.f, p1 = 0.f, p2 = 0.f, p3 = 0.f;
                #pragma unroll
                for (int j = 0; j < 8; ++j) {
                    float4 av = arow[j];
                    p0 += wA[j].x * av.x; p1 += wA[j].y * av.y;
                    p2 += wA[j].z * av.z; p3 += wA[j].w * av.w;
                }
                out[((size_t)(b0 + bl) * FF + f) * DD + d] =
                    ((p0 + p1) + (p2 + p3)) + bv;
            }
            if (fp < WF / 2 - 1) {
                const float4* wn2 = wp + (size_t)(2 * fp + 2) * (DD * DD / 4);
                #pragma unroll
                for (int j = 0; j < 8; ++j) wA[j] = wn2[j];
            }
            #pragma unroll
            for (int bp = 0; bp < NB / 2; ++bp) {             // odd field
                const int bl = (bp << 1) + half;
                const float4* arow = (const float4*)(s_buf + (bl * FF + f + 1) * DD);
                float p0 = 0.f, p1 = 0.f, p2 = 0.f, p3 = 0.f;
                #pragma unroll
                for (int j = 0; j < 8; ++j) {
                    float4 av = arow[j];
                    p0 += wB[j].x * av.x; p1 += wB[j].y * av.y;
                    p2 += wB[j].z * av.z; p3 += wB[j].w * av.w;
                }
                out[((size_t)(b0 + bl) * FF + f + 1) * DD + d] =
                    ((p0 + p1) + (p2 + p3)) + bv;
            }
        }
    }
}

extern "C" void kernel_launch(void* const* d_in, const int* in_sizes, int n_in,
                              void* d_out, int out_size, void* d_ws, size_t ws_size,
                              hipStream_t stream) {
    const float* g    = (const float*)d_in[0];
    const float* h    = (const float*)d_in[1];
    const float* Win  = (const float*)d_in[2];
    const float* Wout = (const float*)d_in[3];
    const float* bias = (const float*)d_in[4];
    float* out = (float*)d_out;

    dim3 block(256);
    dim3 grid(B_TOT / NB);   // 1024 blocks
    graph_layer_fused<<<grid, block, 0, stream>>>(g, h, Win, Wout, bias, out);
}